// Round 2
// baseline (139.443 us; speedup 1.0000x reference)
//
#include <hip/hip_runtime.h>

#define BB 8
#define NN 2048
#define FF 128
#define NL 2
#define SLOPE 0.1f
#define NROW (BB * NN)          // 16384 total rows
#define XS_STRIDE 136           // padded bf16 row stride in LDS

typedef __attribute__((ext_vector_type(8))) short short8;
typedef __attribute__((ext_vector_type(4))) float f32x4;

__device__ __forceinline__ float lrelu(float v) { return v >= 0.f ? v : SLOPE * v; }

// fp32 -> bf16 round-to-nearest-even
__device__ __forceinline__ ushort f2bf(float f) {
    uint u = __float_as_uint(f);
    return (ushort)((u + 0x7fffu + ((u >> 16) & 1u)) >> 16);
}

// ---------------------------------------------------------------------------
// Prep: transpose all 6 weight matrices to bf16 Wt[m][g][f] = W[m][f][g]
// m = l*3 + {0:W3, 1:W4, 2:W5}
// ---------------------------------------------------------------------------
__global__ __launch_bounds__(256) void k_prep(
    const float* __restrict__ W3, const float* __restrict__ W4,
    const float* __restrict__ W5, ushort* __restrict__ Wt)
{
    const int idx = blockIdx.x * 256 + threadIdx.x;   // 0 .. 98303
    const int m = idx >> 14;
    const int rem = idx & 16383;
    const int f = rem & 127;
    const int g = rem >> 7;
    const int l = m / 3, w = m % 3;
    const float* src = (w == 0) ? W3 : (w == 1) ? W4 : W5;
    Wt[m * 16384 + g * 128 + f] = f2bf(src[l * 16384 + f * 128 + g]);
}

// ---------------------------------------------------------------------------
// K1: w1 = lrelu(x@W3+b3) [bf16 row-major], w2t[b][f][j] = lrelu(x@W4+b4)^T,
//     xt[b][g][j] = x^T (bf16), diag[i] = dot(w1_i, w2_i).
// 16 rows / block, grid 1024 (4 blocks/CU -> 16 waves/CU for latency hiding).
// ---------------------------------------------------------------------------
__global__ __launch_bounds__(256) void k_w12(
    const float* __restrict__ x, const ushort* __restrict__ w3t,
    const ushort* __restrict__ w4t, const float* __restrict__ b3,
    const float* __restrict__ b4, ushort* __restrict__ w1b,
    ushort* __restrict__ w2t, ushort* __restrict__ xt,
    float* __restrict__ diag)
{
    __shared__ ushort xs[16 * XS_STRIDE];
    __shared__ float diag_s[16];

    const int tid = threadIdx.x;
    const int row0 = blockIdx.x * 16;
    const int b = row0 >> 11;          // batch
    const int jloc0 = row0 & 2047;     // row within batch

    if (tid < 16) diag_s[tid] = 0.f;

    // stage x tile -> bf16 LDS (row-major, padded): 512 float4, 2 per thread
    const float4* xg4 = (const float4*)(x + (size_t)row0 * FF);
#pragma unroll
    for (int i = 0; i < 2; i++) {
        const int f4 = i * 256 + tid;          // float4 index in tile
        const int row = f4 >> 5;
        const int k = (f4 & 31) * 4;
        float4 v = xg4[f4];
        ushort4 h;
        h.x = f2bf(v.x); h.y = f2bf(v.y); h.z = f2bf(v.z); h.w = f2bf(v.w);
        *(ushort4*)&xs[row * XS_STRIDE + k] = h;
    }
    __syncthreads();

    // write xt[b][g][jloc0..+16] from LDS (transposed read)
    {
        const int g = tid >> 1;
        const int h = tid & 1;
        uint p[4];
#pragma unroll
        for (int jj = 0; jj < 4; jj++) {
            const uint lo = xs[(h * 8 + jj * 2) * XS_STRIDE + g];
            const uint hi = xs[(h * 8 + jj * 2 + 1) * XS_STRIDE + g];
            p[jj] = lo | (hi << 16);
        }
        uint4* dst = (uint4*)&xt[(size_t)b * (FF * NN) + (size_t)g * NN + jloc0 + h * 8];
        dst[0] = make_uint4(p[0], p[1], p[2], p[3]);
    }

    const int lane = tid & 63;
    const int wave = tid >> 6;
    const int c = lane & 15;
    const int quad = lane >> 4;
    const int ct0 = wave * 2;

    f32x4 acc1[2], acc2[2];
#pragma unroll
    for (int ct = 0; ct < 2; ct++) { acc1[ct] = (f32x4)0.f; acc2[ct] = (f32x4)0.f; }

#pragma unroll
    for (int kk = 0; kk < 4; kk++) {
        short8 a0 = *(const short8*)&xs[c * XS_STRIDE + kk * 32 + quad * 8];
#pragma unroll
        for (int ct = 0; ct < 2; ct++) {
            const int n = (ct0 + ct) * 16 + c;
            short8 bf3 = *(const short8*)&w3t[n * 128 + kk * 32 + quad * 8];
            short8 bf4 = *(const short8*)&w4t[n * 128 + kk * 32 + quad * 8];
            acc1[ct] = __builtin_amdgcn_mfma_f32_16x16x32_bf16(a0, bf3, acc1[ct], 0, 0, 0);
            acc2[ct] = __builtin_amdgcn_mfma_f32_16x16x32_bf16(a0, bf4, acc2[ct], 0, 0, 0);
        }
    }

    float dpar[4];
#pragma unroll
    for (int r = 0; r < 4; r++) dpar[r] = 0.f;

#pragma unroll
    for (int ct = 0; ct < 2; ct++) {
        const int gcol = (ct0 + ct) * 16 + c;
        const float bb3 = b3[gcol], bb4 = b4[gcol];
        ushort w2p[4];
#pragma unroll
        for (int r = 0; r < 4; r++) {
            const float v1 = lrelu(acc1[ct][r] + bb3);
            const float v2 = lrelu(acc2[ct][r] + bb4);
            const int grow = row0 + quad * 4 + r;
            w1b[(size_t)grow * FF + gcol] = f2bf(v1);
            w2p[r] = f2bf(v2);
            dpar[r] += v1 * v2;
        }
        const uint lo = (uint)w2p[0] | ((uint)w2p[1] << 16);
        const uint hi = (uint)w2p[2] | ((uint)w2p[3] << 16);
        uint2* dst = (uint2*)&w2t[(size_t)b * (FF * NN) + (size_t)gcol * NN +
                                  jloc0 + quad * 4];
        *dst = make_uint2(lo, hi);
    }

    // diag: reduce dpar across the 16 lanes of each quad-row group
#pragma unroll
    for (int r = 0; r < 4; r++) {
        float dp = dpar[r];
        dp += __shfl_xor(dp, 1, 64);
        dp += __shfl_xor(dp, 2, 64);
        dp += __shfl_xor(dp, 4, 64);
        dp += __shfl_xor(dp, 8, 64);
        if (c == 0) atomicAdd(&diag_s[quad * 4 + r], dp);
    }
    __syncthreads();
    if (tid < 16) diag[row0 + tid] = diag_s[tid];
}

// ---------------------------------------------------------------------------
// K2: St[b][g][f] = bf16( sum_j xt[b][g][j] * w2t[b][f][j] )
// grid = 8 batch x 8 g-groups(16g) x 8 f-strips(16f) = 512 blocks x 512 thr.
// 8 waves split K (256 each); LDS reduce; write bf16 directly.
// 2 blocks/CU x 8 waves = 16 waves/CU.
// ---------------------------------------------------------------------------
__global__ __launch_bounds__(512) void k_S2(
    const ushort* __restrict__ xt, const ushort* __restrict__ w2t,
    ushort* __restrict__ St)
{
    __shared__ float red[8][256];   // 8 KB
    const int tid = threadIdx.x;
    const int lane = tid & 63;
    const int wave = tid >> 6;
    const int c = lane & 15;
    const int quad = lane >> 4;

    const int b  = blockIdx.x >> 6;         // 0..7
    const int gq = (blockIdx.x >> 3) & 7;   // g-group (16 g)
    const int fs = blockIdx.x & 7;          // f-strip (16 f)

    const ushort* xtb = xt + (size_t)b * (FF * NN);
    const ushort* w2b = w2t + (size_t)b * (FF * NN);

    const int j0 = wave * 256 + quad * 8;
    const ushort* a0p = &xtb[(gq * 16 + c) * NN + j0];
    const ushort* bp  = &w2b[(fs * 16 + c) * NN + j0];

    f32x4 acc0 = (f32x4)0.f;
#pragma unroll
    for (int it = 0; it < 8; it++) {
        short8 a0 = *(const short8*)(a0p + it * 32);
        short8 bf = *(const short8*)(bp + it * 32);
        acc0 = __builtin_amdgcn_mfma_f32_16x16x32_bf16(a0, bf, acc0, 0, 0, 0);
    }

#pragma unroll
    for (int r = 0; r < 4; r++) {
        red[wave][(quad * 4 + r) * 16 + c] = acc0[r];
    }
    __syncthreads();

    if (tid < 256) {
        float s = 0.f;
#pragma unroll
        for (int w = 0; w < 8; w++) s += red[w][tid];
        const int gl = tid >> 4;
        const int fl = tid & 15;
        St[(size_t)b * (FF * FF) + (size_t)(gq * 16 + gl) * FF + fs * 16 + fl] = f2bf(s);
    }
}

// ---------------------------------------------------------------------------
// K3: msg = (w1 @ S - diag*x)/(N-1);  out = lrelu(msg @ W5 + b5) + x
// 16 rows / block, grid 1024.
// ---------------------------------------------------------------------------
__global__ __launch_bounds__(256) void k_out(
    const float* __restrict__ x, const ushort* __restrict__ w1b,
    const ushort* __restrict__ St, const float* __restrict__ diag,
    const ushort* __restrict__ w5t, const float* __restrict__ b5,
    float* __restrict__ out)
{
    __shared__ ushort w1s[16 * XS_STRIDE];
    __shared__ ushort ms[16 * XS_STRIDE];

    const int tid = threadIdx.x;
    const int row0 = blockIdx.x * 16;
    const int b = row0 >> 11;
    const ushort* Sb = St + (size_t)b * (FF * FF);

    // stage w1 tile (16x128 bf16 = 256 short8, 1 per thread)
    {
        const int off = tid * 8;
        const int row = off >> 7;
        const int k = off & 127;
        short8 v = *(const short8*)&w1b[(size_t)row0 * FF + off];
        *(short8*)&w1s[row * XS_STRIDE + k] = v;
    }
    __syncthreads();

    const int lane = tid & 63;
    const int wave = tid >> 6;
    const int c = lane & 15;
    const int quad = lane >> 4;
    const int ct0 = wave * 2;

    f32x4 accm[2];
#pragma unroll
    for (int ct = 0; ct < 2; ct++) accm[ct] = (f32x4)0.f;

#pragma unroll
    for (int kk = 0; kk < 4; kk++) {
        short8 a0 = *(const short8*)&w1s[c * XS_STRIDE + kk * 32 + quad * 8];
#pragma unroll
        for (int ct = 0; ct < 2; ct++) {
            const int n = (ct0 + ct) * 16 + c;
            short8 bf = *(const short8*)&Sb[n * 128 + kk * 32 + quad * 8];
            accm[ct] = __builtin_amdgcn_mfma_f32_16x16x32_bf16(a0, bf, accm[ct], 0, 0, 0);
        }
    }

    const float inv = 1.f / (float)(NN - 1);
    float xsv[2][4];
    float dg[4];
#pragma unroll
    for (int r = 0; r < 4; r++) dg[r] = diag[row0 + quad * 4 + r];
#pragma unroll
    for (int ct = 0; ct < 2; ct++) {
        const int gcol = (ct0 + ct) * 16 + c;
#pragma unroll
        for (int r = 0; r < 4; r++) {
            const int lrow = quad * 4 + r;
            const float xv = x[(size_t)(row0 + lrow) * FF + gcol];
            xsv[ct][r] = xv;
            const float m = (accm[ct][r] - dg[r] * xv) * inv;
            ms[lrow * XS_STRIDE + gcol] = f2bf(m);
        }
    }
    __syncthreads();

    f32x4 acc2[2];
#pragma unroll
    for (int ct = 0; ct < 2; ct++) acc2[ct] = (f32x4)0.f;

#pragma unroll
    for (int kk = 0; kk < 4; kk++) {
        short8 a0 = *(const short8*)&ms[c * XS_STRIDE + kk * 32 + quad * 8];
#pragma unroll
        for (int ct = 0; ct < 2; ct++) {
            const int n = (ct0 + ct) * 16 + c;
            short8 bf = *(const short8*)&w5t[n * 128 + kk * 32 + quad * 8];
            acc2[ct] = __builtin_amdgcn_mfma_f32_16x16x32_bf16(a0, bf, acc2[ct], 0, 0, 0);
        }
    }

#pragma unroll
    for (int ct = 0; ct < 2; ct++) {
        const int gcol = (ct0 + ct) * 16 + c;
        const float bb = b5[gcol];
#pragma unroll
        for (int r = 0; r < 4; r++) {
            const int grow = row0 + quad * 4 + r;
            out[(size_t)grow * FF + gcol] = lrelu(acc2[ct][r] + bb) + xsv[ct][r];
        }
    }
}

// ---------------------------------------------------------------------------
// K4: fused k_out(layer l) + k_w12(layer l+1), 16-row tiles, grid 1024.
// Phase A = k_out keeping the bf16 output tile in LDS; Phase B runs next
// layer's w1/w2/xt/diag from that tile without reloading.
// Aliasing note: each block touches only its own 16 rows of w1b/diag, so
// reading layer-l values and writing layer-(l+1) values in place is safe.
// ---------------------------------------------------------------------------
__global__ __launch_bounds__(256) void k_out_w12(
    const float* __restrict__ x, const ushort* __restrict__ w1b_in,
    const ushort* __restrict__ St, const float* __restrict__ diag_in,
    const ushort* __restrict__ w5t, const float* __restrict__ b5,
    float* __restrict__ out,
    const ushort* __restrict__ w3t, const ushort* __restrict__ w4t,
    const float* __restrict__ b3, const float* __restrict__ b4,
    ushort* __restrict__ w1b, ushort* __restrict__ w2t,
    ushort* __restrict__ xt, float* __restrict__ diag)
{
    __shared__ ushort sA[16 * XS_STRIDE];   // w1 tile, then out tile (bf16)
    __shared__ ushort sB[16 * XS_STRIDE];   // msg tile
    __shared__ float diag_s[16];

    const int tid = threadIdx.x;
    const int row0 = blockIdx.x * 16;
    const int b = row0 >> 11;
    const int jloc0 = row0 & 2047;
    const ushort* Sb = St + (size_t)b * (FF * FF);

    if (tid < 16) diag_s[tid] = 0.f;

    // ---- Phase A: out = lrelu((w1@S - diag*x)/(N-1) @ W5 + b5) + x ----
    {
        const int off = tid * 8;
        const int row = off >> 7;
        const int k = off & 127;
        short8 v = *(const short8*)&w1b_in[(size_t)row0 * FF + off];
        *(short8*)&sA[row * XS_STRIDE + k] = v;
    }
    __syncthreads();

    const int lane = tid & 63;
    const int wave = tid >> 6;
    const int c = lane & 15;
    const int quad = lane >> 4;
    const int ct0 = wave * 2;

    f32x4 accm[2];
#pragma unroll
    for (int ct = 0; ct < 2; ct++) accm[ct] = (f32x4)0.f;

#pragma unroll
    for (int kk = 0; kk < 4; kk++) {
        short8 a0 = *(const short8*)&sA[c * XS_STRIDE + kk * 32 + quad * 8];
#pragma unroll
        for (int ct = 0; ct < 2; ct++) {
            const int n = (ct0 + ct) * 16 + c;
            short8 bf = *(const short8*)&Sb[n * 128 + kk * 32 + quad * 8];
            accm[ct] = __builtin_amdgcn_mfma_f32_16x16x32_bf16(a0, bf, accm[ct], 0, 0, 0);
        }
    }

    const float inv = 1.f / (float)(NN - 1);
    float xsv[2][4];
    float dg[4];
#pragma unroll
    for (int r = 0; r < 4; r++) dg[r] = diag_in[row0 + quad * 4 + r];
#pragma unroll
    for (int ct = 0; ct < 2; ct++) {
        const int gcol = (ct0 + ct) * 16 + c;
#pragma unroll
        for (int r = 0; r < 4; r++) {
            const int lrow = quad * 4 + r;
            const float xv = x[(size_t)(row0 + lrow) * FF + gcol];
            xsv[ct][r] = xv;
            const float m = (accm[ct][r] - dg[r] * xv) * inv;
            sB[lrow * XS_STRIDE + gcol] = f2bf(m);
        }
    }
    __syncthreads();   // sB ready; sA (w1 tile) still holds w1 but is now dead

    f32x4 acc2[2];
#pragma unroll
    for (int ct = 0; ct < 2; ct++) acc2[ct] = (f32x4)0.f;

#pragma unroll
    for (int kk = 0; kk < 4; kk++) {
        short8 a0 = *(const short8*)&sB[c * XS_STRIDE + kk * 32 + quad * 8];
#pragma unroll
        for (int ct = 0; ct < 2; ct++) {
            const int n = (ct0 + ct) * 16 + c;
            short8 bf = *(const short8*)&w5t[n * 128 + kk * 32 + quad * 8];
            acc2[ct] = __builtin_amdgcn_mfma_f32_16x16x32_bf16(a0, bf, acc2[ct], 0, 0, 0);
        }
    }

    // epilogue: write out (fp32 global) + stash bf16 out tile in sA
#pragma unroll
    for (int ct = 0; ct < 2; ct++) {
        const int gcol = (ct0 + ct) * 16 + c;
        const float bb = b5[gcol];
#pragma unroll
        for (int r = 0; r < 4; r++) {
            const int lrow = quad * 4 + r;
            const float ov = lrelu(acc2[ct][r] + bb) + xsv[ct][r];
            out[(size_t)(row0 + lrow) * FF + gcol] = ov;
            sA[lrow * XS_STRIDE + gcol] = f2bf(ov);
        }
    }
    __syncthreads();   // sA = bf16 out tile, visible to all waves

    // ---- Phase B: next layer's w1/w2/xt/diag from sA ----
    {
        const int g = tid >> 1;
        const int h = tid & 1;
        uint p[4];
#pragma unroll
        for (int jj = 0; jj < 4; jj++) {
            const uint lo = sA[(h * 8 + jj * 2) * XS_STRIDE + g];
            const uint hi = sA[(h * 8 + jj * 2 + 1) * XS_STRIDE + g];
            p[jj] = lo | (hi << 16);
        }
        uint4* dst = (uint4*)&xt[(size_t)b * (FF * NN) + (size_t)g * NN + jloc0 + h * 8];
        dst[0] = make_uint4(p[0], p[1], p[2], p[3]);
    }

    f32x4 acc1n[2], acc2n[2];
#pragma unroll
    for (int ct = 0; ct < 2; ct++) { acc1n[ct] = (f32x4)0.f; acc2n[ct] = (f32x4)0.f; }

#pragma unroll
    for (int kk = 0; kk < 4; kk++) {
        short8 a0 = *(const short8*)&sA[c * XS_STRIDE + kk * 32 + quad * 8];
#pragma unroll
        for (int ct = 0; ct < 2; ct++) {
            const int n = (ct0 + ct) * 16 + c;
            short8 bf3 = *(const short8*)&w3t[n * 128 + kk * 32 + quad * 8];
            short8 bf4 = *(const short8*)&w4t[n * 128 + kk * 32 + quad * 8];
            acc1n[ct] = __builtin_amdgcn_mfma_f32_16x16x32_bf16(a0, bf3, acc1n[ct], 0, 0, 0);
            acc2n[ct] = __builtin_amdgcn_mfma_f32_16x16x32_bf16(a0, bf4, acc2n[ct], 0, 0, 0);
        }
    }

    float dpar[4];
#pragma unroll
    for (int r = 0; r < 4; r++) dpar[r] = 0.f;

#pragma unroll
    for (int ct = 0; ct < 2; ct++) {
        const int gcol = (ct0 + ct) * 16 + c;
        const float bb3 = b3[gcol], bb4 = b4[gcol];
        ushort w2p[4];
#pragma unroll
        for (int r = 0; r < 4; r++) {
            const float v1 = lrelu(acc1n[ct][r] + bb3);
            const float v2 = lrelu(acc2n[ct][r] + bb4);
            const int grow = row0 + quad * 4 + r;
            w1b[(size_t)grow * FF + gcol] = f2bf(v1);
            w2p[r] = f2bf(v2);
            dpar[r] += v1 * v2;
        }
        const uint lo = (uint)w2p[0] | ((uint)w2p[1] << 16);
        const uint hi = (uint)w2p[2] | ((uint)w2p[3] << 16);
        uint2* dst = (uint2*)&w2t[(size_t)b * (FF * NN) + (size_t)gcol * NN +
                                  jloc0 + quad * 4];
        *dst = make_uint2(lo, hi);
    }

#pragma unroll
    for (int r = 0; r < 4; r++) {
        float dp = dpar[r];
        dp += __shfl_xor(dp, 1, 64);
        dp += __shfl_xor(dp, 2, 64);
        dp += __shfl_xor(dp, 4, 64);
        dp += __shfl_xor(dp, 8, 64);
        if (c == 0) atomicAdd(&diag_s[quad * 4 + r], dp);
    }
    __syncthreads();
    if (tid < 16) diag[row0 + tid] = diag_s[tid];
}

// ---------------------------------------------------------------------------
extern "C" void kernel_launch(void* const* d_in, const int* in_sizes, int n_in,
                              void* d_out, int out_size, void* d_ws, size_t ws_size,
                              hipStream_t stream)
{
    const float* x  = (const float*)d_in[0];
    const float* W3 = (const float*)d_in[1];
    const float* b3 = (const float*)d_in[2];
    const float* W4 = (const float*)d_in[3];
    const float* b4 = (const float*)d_in[4];
    const float* W5 = (const float*)d_in[5];
    const float* b5 = (const float*)d_in[6];
    float* out = (float*)d_out;

    char* ws = (char*)d_ws;
    ushort* w1b   = (ushort*)(ws);                       // 4 MB bf16 [16384][128]
    ushort* w2t   = (ushort*)(ws + ((size_t)4  << 20));  // 4 MB bf16 [8][128][2048]
    ushort* xt    = (ushort*)(ws + ((size_t)8  << 20));  // 4 MB bf16 [8][128][2048]
    float*  diag  = (float*) (ws + ((size_t)12 << 20));  // 64 KB fp32 [16384]
    ushort* St    = (ushort*)(ws + ((size_t)13 << 20));  // 256 KB bf16 [8][128][128]
    ushort* Wt    = (ushort*)(ws + ((size_t)14 << 20));  // 192 KB bf16 [6][128][128]

    const ushort* w3t0 = Wt;
    const ushort* w4t0 = Wt + 16384;
    const ushort* w5t0 = Wt + 2 * 16384;
    const ushort* w3t1 = Wt + 3 * 16384;
    const ushort* w4t1 = Wt + 4 * 16384;
    const ushort* w5t1 = Wt + 5 * 16384;

    const int rowBlocks = NROW / 16;   // 1024

    k_prep<<<384, 256, 0, stream>>>(W3, W4, W5, Wt);

    // Layer 0
    k_w12<<<rowBlocks, 256, 0, stream>>>(x, w3t0, w4t0, b3, b4, w1b, w2t, xt, diag);
    k_S2<<<512, 512, 0, stream>>>(xt, w2t, St);
    // Layer 0 output + Layer 1 w12, fused
    k_out_w12<<<rowBlocks, 256, 0, stream>>>(x, w1b, St, diag, w5t0, b5, out,
                                             w3t1, w4t1, b3 + FF, b4 + FF,
                                             w1b, w2t, xt, diag);
    // Layer 1
    k_S2<<<512, 512, 0, stream>>>(xt, w2t, St);
    k_out<<<rowBlocks, 256, 0, stream>>>(out, w1b, St, diag, w5t1, b5 + FF, out);
}

// Round 3
// 120.556 us; speedup vs baseline: 1.1567x; 1.1567x over previous
//
#include <hip/hip_runtime.h>

#define BB 8
#define NN 2048
#define FF 128
#define NL 2
#define SLOPE 0.1f
#define NROW (BB * NN)          // 16384 total rows
#define XS_STRIDE 136           // padded bf16 row stride in LDS

typedef __attribute__((ext_vector_type(8))) short short8;
typedef __attribute__((ext_vector_type(4))) float f32x4;

__device__ __forceinline__ float lrelu(float v) { return v >= 0.f ? v : SLOPE * v; }

// fp32 -> bf16 round-to-nearest-even
__device__ __forceinline__ ushort f2bf(float f) {
    uint u = __float_as_uint(f);
    return (ushort)((u + 0x7fffu + ((u >> 16) & 1u)) >> 16);
}

// ---------------------------------------------------------------------------
// Prep: transpose all 6 weight matrices to bf16 Wt[m][g][f] = W[m][f][g]
// m = l*3 + {0:W3, 1:W4, 2:W5}
// ---------------------------------------------------------------------------
__global__ __launch_bounds__(256) void k_prep(
    const float* __restrict__ W3, const float* __restrict__ W4,
    const float* __restrict__ W5, ushort* __restrict__ Wt)
{
    const int idx = blockIdx.x * 256 + threadIdx.x;   // 0 .. 98303
    const int m = idx >> 14;
    const int rem = idx & 16383;
    const int f = rem & 127;
    const int g = rem >> 7;
    const int l = m / 3, w = m % 3;
    const float* src = (w == 0) ? W3 : (w == 1) ? W4 : W5;
    Wt[m * 16384 + g * 128 + f] = f2bf(src[l * 16384 + f * 128 + g]);
}

// ---------------------------------------------------------------------------
// K1: w1 = lrelu(x@W3+b3) [bf16 row-major], w2t[b][f][j] = lrelu(x@W4+b4)^T,
//     xt[b][g][j] = x^T (bf16), diag[i] = dot(w1_i, w2_i).
// 64 rows / block, 512 threads (8 waves, 1 column-tile each), grid 256.
// Weight matrices read ONCE per block (64 KB) -> amortized over 64 rows.
// ---------------------------------------------------------------------------
__global__ __launch_bounds__(512) void k_w12(
    const float* __restrict__ x, const ushort* __restrict__ w3t,
    const ushort* __restrict__ w4t, const float* __restrict__ b3,
    const float* __restrict__ b4, ushort* __restrict__ w1b,
    ushort* __restrict__ w2t, ushort* __restrict__ xt,
    float* __restrict__ diag)
{
    __shared__ ushort xs[64 * XS_STRIDE];   // 17408 B
    __shared__ float diag_s[64];

    const int tid = threadIdx.x;            // 0..511
    const int row0 = blockIdx.x * 64;
    const int b = row0 >> 11;               // batch
    const int jloc0 = row0 & 2047;          // row within batch

    if (tid < 64) diag_s[tid] = 0.f;

    // stage x tile -> bf16 LDS (row-major, padded): 2048 float4, 4 per thread
    const float4* xg4 = (const float4*)(x + (size_t)row0 * FF);
#pragma unroll
    for (int i = 0; i < 4; i++) {
        const int f4 = i * 512 + tid;          // float4 index in tile
        const int row = f4 >> 5;
        const int k = (f4 & 31) * 4;
        float4 v = xg4[f4];
        ushort4 h;
        h.x = f2bf(v.x); h.y = f2bf(v.y); h.z = f2bf(v.z); h.w = f2bf(v.w);
        *(ushort4*)&xs[row * XS_STRIDE + k] = h;
    }
    __syncthreads();

    // write xt[b][g][jloc0..+64] from LDS (transposed read), 16 j per thread
    {
        const int g = tid >> 2;
        const int h = tid & 3;
        uint p[8];
#pragma unroll
        for (int jj = 0; jj < 8; jj++) {
            const uint lo = xs[(h * 16 + jj * 2) * XS_STRIDE + g];
            const uint hi = xs[(h * 16 + jj * 2 + 1) * XS_STRIDE + g];
            p[jj] = lo | (hi << 16);
        }
        uint4* dst = (uint4*)&xt[(size_t)b * (FF * NN) + (size_t)g * NN + jloc0 + h * 16];
        dst[0] = make_uint4(p[0], p[1], p[2], p[3]);
        dst[1] = make_uint4(p[4], p[5], p[6], p[7]);
    }

    const int lane = tid & 63;
    const int wave = tid >> 6;     // 0..7 = column tile (16 cols each)
    const int c = lane & 15;
    const int quad = lane >> 4;
    const int n = wave * 16 + c;   // weight/fragment column index

    f32x4 acc1[4], acc2[4];
#pragma unroll
    for (int rt = 0; rt < 4; rt++) { acc1[rt] = (f32x4)0.f; acc2[rt] = (f32x4)0.f; }

#pragma unroll
    for (int kk = 0; kk < 4; kk++) {
        short8 bf3 = *(const short8*)&w3t[n * 128 + kk * 32 + quad * 8];
        short8 bf4 = *(const short8*)&w4t[n * 128 + kk * 32 + quad * 8];
#pragma unroll
        for (int rt = 0; rt < 4; rt++) {
            short8 a = *(const short8*)&xs[(rt * 16 + c) * XS_STRIDE + kk * 32 + quad * 8];
            acc1[rt] = __builtin_amdgcn_mfma_f32_16x16x32_bf16(a, bf3, acc1[rt], 0, 0, 0);
            acc2[rt] = __builtin_amdgcn_mfma_f32_16x16x32_bf16(a, bf4, acc2[rt], 0, 0, 0);
        }
    }

    const int gcol = wave * 16 + c;
    const float bb3 = b3[gcol], bb4 = b4[gcol];
    float dpar[4][4];

#pragma unroll
    for (int rt = 0; rt < 4; rt++) {
        ushort w2p[4];
#pragma unroll
        for (int r = 0; r < 4; r++) {
            const float v1 = lrelu(acc1[rt][r] + bb3);
            const float v2 = lrelu(acc2[rt][r] + bb4);
            const int grow = row0 + rt * 16 + quad * 4 + r;
            w1b[(size_t)grow * FF + gcol] = f2bf(v1);
            w2p[r] = f2bf(v2);
            dpar[rt][r] = v1 * v2;
        }
        const uint lo = (uint)w2p[0] | ((uint)w2p[1] << 16);
        const uint hi = (uint)w2p[2] | ((uint)w2p[3] << 16);
        uint2* dst = (uint2*)&w2t[(size_t)b * (FF * NN) + (size_t)gcol * NN +
                                  jloc0 + rt * 16 + quad * 4];
        *dst = make_uint2(lo, hi);
    }

    // diag: reduce dpar across the 16 c-lanes of each quad-row group
#pragma unroll
    for (int rt = 0; rt < 4; rt++) {
#pragma unroll
        for (int r = 0; r < 4; r++) {
            float dp = dpar[rt][r];
            dp += __shfl_xor(dp, 1, 64);
            dp += __shfl_xor(dp, 2, 64);
            dp += __shfl_xor(dp, 4, 64);
            dp += __shfl_xor(dp, 8, 64);
            if (c == 0) atomicAdd(&diag_s[rt * 16 + quad * 4 + r], dp);
        }
    }
    __syncthreads();
    if (tid < 64) diag[row0 + tid] = diag_s[tid];
}

// ---------------------------------------------------------------------------
// K2: St[b][g][f] = bf16( sum_j xt[b][g][j] * w2t[b][f][j] )
// grid = 8 batch x 4 g-quarters x 8 f-strips = 256 blocks (round-0 shape).
// Waves split K (512 each); LDS reduce; write bf16 directly.
// ---------------------------------------------------------------------------
__global__ __launch_bounds__(256) void k_S2(
    const ushort* __restrict__ xt, const ushort* __restrict__ w2t,
    ushort* __restrict__ St)
{
    __shared__ float red[4][512];   // 8 KB
    const int tid = threadIdx.x;
    const int lane = tid & 63;
    const int wave = tid >> 6;
    const int c = lane & 15;
    const int quad = lane >> 4;

    const int b  = blockIdx.x >> 5;         // 0..7
    const int gq = (blockIdx.x >> 3) & 3;   // g-quarter (32 g)
    const int fs = blockIdx.x & 7;          // f-strip (16 f)

    const ushort* xtb = xt + (size_t)b * (FF * NN);
    const ushort* w2b = w2t + (size_t)b * (FF * NN);

    const int j0 = wave * 512 + quad * 8;
    const ushort* a0p = &xtb[(gq * 32 + c) * NN + j0];
    const ushort* a1p = &xtb[(gq * 32 + 16 + c) * NN + j0];
    const ushort* bp  = &w2b[(fs * 16 + c) * NN + j0];

    f32x4 acc0 = (f32x4)0.f, acc1 = (f32x4)0.f;
#pragma unroll
    for (int it = 0; it < 16; it++) {
        short8 a0 = *(const short8*)(a0p + it * 32);
        short8 a1 = *(const short8*)(a1p + it * 32);
        short8 bf = *(const short8*)(bp + it * 32);
        acc0 = __builtin_amdgcn_mfma_f32_16x16x32_bf16(a0, bf, acc0, 0, 0, 0);
        acc1 = __builtin_amdgcn_mfma_f32_16x16x32_bf16(a1, bf, acc1, 0, 0, 0);
    }

#pragma unroll
    for (int r = 0; r < 4; r++) {
        red[wave][(quad * 4 + r) * 16 + c] = acc0[r];
        red[wave][(16 + quad * 4 + r) * 16 + c] = acc1[r];
    }
    __syncthreads();

#pragma unroll
    for (int i = 0; i < 2; i++) {
        const int idx = i * 256 + tid;
        const float s = red[0][idx] + red[1][idx] + red[2][idx] + red[3][idx];
        const int gl = idx >> 4;
        const int fl = idx & 15;
        St[(size_t)b * (FF * FF) + (size_t)(gq * 32 + gl) * FF + fs * 16 + fl] = f2bf(s);
    }
}

// ---------------------------------------------------------------------------
// K3: msg = (w1 @ S - diag*x)/(N-1);  out = lrelu(msg @ W5 + b5) + x
// 64 rows / block, 512 threads, grid 256.
// ---------------------------------------------------------------------------
__global__ __launch_bounds__(512) void k_out(
    const float* __restrict__ x, const ushort* __restrict__ w1b,
    const ushort* __restrict__ St, const float* __restrict__ diag,
    const ushort* __restrict__ w5t, const float* __restrict__ b5,
    float* __restrict__ out)
{
    __shared__ ushort w1s[64 * XS_STRIDE];
    __shared__ ushort ms[64 * XS_STRIDE];

    const int tid = threadIdx.x;
    const int row0 = blockIdx.x * 64;
    const int b = row0 >> 11;
    const ushort* Sb = St + (size_t)b * (FF * FF);

    // stage w1 tile (64x128 bf16 = 1024 short8, 2 per thread)
#pragma unroll
    for (int i = 0; i < 2; i++) {
        const int off = (i * 512 + tid) * 8;
        const int row = off >> 7;
        const int k = off & 127;
        short8 v = *(const short8*)&w1b[(size_t)row0 * FF + off];
        *(short8*)&w1s[row * XS_STRIDE + k] = v;
    }
    __syncthreads();

    const int lane = tid & 63;
    const int wave = tid >> 6;
    const int c = lane & 15;
    const int quad = lane >> 4;
    const int n = wave * 16 + c;

    f32x4 accm[4];
#pragma unroll
    for (int rt = 0; rt < 4; rt++) accm[rt] = (f32x4)0.f;

#pragma unroll
    for (int kk = 0; kk < 4; kk++) {
        short8 bf = *(const short8*)&Sb[n * 128 + kk * 32 + quad * 8];
#pragma unroll
        for (int rt = 0; rt < 4; rt++) {
            short8 a = *(const short8*)&w1s[(rt * 16 + c) * XS_STRIDE + kk * 32 + quad * 8];
            accm[rt] = __builtin_amdgcn_mfma_f32_16x16x32_bf16(a, bf, accm[rt], 0, 0, 0);
        }
    }

    const float inv = 1.f / (float)(NN - 1);
    const int gcol = wave * 16 + c;
    float xsv[4][4];
#pragma unroll
    for (int rt = 0; rt < 4; rt++) {
        float dg[4];
#pragma unroll
        for (int r = 0; r < 4; r++) dg[r] = diag[row0 + rt * 16 + quad * 4 + r];
#pragma unroll
        for (int r = 0; r < 4; r++) {
            const int lrow = rt * 16 + quad * 4 + r;
            const float xv = x[(size_t)(row0 + lrow) * FF + gcol];
            xsv[rt][r] = xv;
            const float m = (accm[rt][r] - dg[r] * xv) * inv;
            ms[lrow * XS_STRIDE + gcol] = f2bf(m);
        }
    }
    __syncthreads();

    f32x4 acc2[4];
#pragma unroll
    for (int rt = 0; rt < 4; rt++) acc2[rt] = (f32x4)0.f;

#pragma unroll
    for (int kk = 0; kk < 4; kk++) {
        short8 bf = *(const short8*)&w5t[n * 128 + kk * 32 + quad * 8];
#pragma unroll
        for (int rt = 0; rt < 4; rt++) {
            short8 a = *(const short8*)&ms[(rt * 16 + c) * XS_STRIDE + kk * 32 + quad * 8];
            acc2[rt] = __builtin_amdgcn_mfma_f32_16x16x32_bf16(a, bf, acc2[rt], 0, 0, 0);
        }
    }

    const float bb = b5[gcol];
#pragma unroll
    for (int rt = 0; rt < 4; rt++) {
#pragma unroll
        for (int r = 0; r < 4; r++) {
            const int grow = row0 + rt * 16 + quad * 4 + r;
            out[(size_t)grow * FF + gcol] = lrelu(acc2[rt][r] + bb) + xsv[rt][r];
        }
    }
}

// ---------------------------------------------------------------------------
// K4: fused k_out(layer l) + k_w12(layer l+1), 64-row tiles, 512 thr, grid 256.
// Phase A = k_out keeping the bf16 output tile in LDS; Phase B runs next
// layer's w1/w2/xt/diag from that tile without reloading.
// Aliasing note: each block touches only its own 64 rows of w1b/diag, so
// reading layer-l values and writing layer-(l+1) values in place is safe.
// ---------------------------------------------------------------------------
__global__ __launch_bounds__(512) void k_out_w12(
    const float* __restrict__ x, const ushort* __restrict__ w1b_in,
    const ushort* __restrict__ St, const float* __restrict__ diag_in,
    const ushort* __restrict__ w5t, const float* __restrict__ b5,
    float* __restrict__ out,
    const ushort* __restrict__ w3t, const ushort* __restrict__ w4t,
    const float* __restrict__ b3, const float* __restrict__ b4,
    ushort* __restrict__ w1b, ushort* __restrict__ w2t,
    ushort* __restrict__ xt, float* __restrict__ diag)
{
    __shared__ ushort sA[64 * XS_STRIDE];   // w1 tile, then out tile (bf16)
    __shared__ ushort sB[64 * XS_STRIDE];   // msg tile
    __shared__ float diag_s[64];

    const int tid = threadIdx.x;
    const int row0 = blockIdx.x * 64;
    const int b = row0 >> 11;
    const int jloc0 = row0 & 2047;
    const ushort* Sb = St + (size_t)b * (FF * FF);

    if (tid < 64) diag_s[tid] = 0.f;

    // ---- Phase A: out = lrelu((w1@S - diag*x)/(N-1) @ W5 + b5) + x ----
#pragma unroll
    for (int i = 0; i < 2; i++) {
        const int off = (i * 512 + tid) * 8;
        const int row = off >> 7;
        const int k = off & 127;
        short8 v = *(const short8*)&w1b_in[(size_t)row0 * FF + off];
        *(short8*)&sA[row * XS_STRIDE + k] = v;
    }
    __syncthreads();

    const int lane = tid & 63;
    const int wave = tid >> 6;
    const int c = lane & 15;
    const int quad = lane >> 4;
    const int n = wave * 16 + c;
    const int gcol = wave * 16 + c;

    f32x4 accm[4];
#pragma unroll
    for (int rt = 0; rt < 4; rt++) accm[rt] = (f32x4)0.f;

#pragma unroll
    for (int kk = 0; kk < 4; kk++) {
        short8 bf = *(const short8*)&Sb[n * 128 + kk * 32 + quad * 8];
#pragma unroll
        for (int rt = 0; rt < 4; rt++) {
            short8 a = *(const short8*)&sA[(rt * 16 + c) * XS_STRIDE + kk * 32 + quad * 8];
            accm[rt] = __builtin_amdgcn_mfma_f32_16x16x32_bf16(a, bf, accm[rt], 0, 0, 0);
        }
    }

    const float inv = 1.f / (float)(NN - 1);
    float xsv[4][4];
#pragma unroll
    for (int rt = 0; rt < 4; rt++) {
        float dg[4];
#pragma unroll
        for (int r = 0; r < 4; r++) dg[r] = diag_in[row0 + rt * 16 + quad * 4 + r];
#pragma unroll
        for (int r = 0; r < 4; r++) {
            const int lrow = rt * 16 + quad * 4 + r;
            const float xv = x[(size_t)(row0 + lrow) * FF + gcol];
            xsv[rt][r] = xv;
            const float m = (accm[rt][r] - dg[r] * xv) * inv;
            sB[lrow * XS_STRIDE + gcol] = f2bf(m);
        }
    }
    __syncthreads();   // sB ready; sA (w1 tile) now dead

    f32x4 acc2[4];
#pragma unroll
    for (int rt = 0; rt < 4; rt++) acc2[rt] = (f32x4)0.f;

#pragma unroll
    for (int kk = 0; kk < 4; kk++) {
        short8 bf = *(const short8*)&w5t[n * 128 + kk * 32 + quad * 8];
#pragma unroll
        for (int rt = 0; rt < 4; rt++) {
            short8 a = *(const short8*)&sB[(rt * 16 + c) * XS_STRIDE + kk * 32 + quad * 8];
            acc2[rt] = __builtin_amdgcn_mfma_f32_16x16x32_bf16(a, bf, acc2[rt], 0, 0, 0);
        }
    }

    // epilogue: write out (fp32 global) + stash bf16 out tile in sA
    const float bb = b5[gcol];
#pragma unroll
    for (int rt = 0; rt < 4; rt++) {
#pragma unroll
        for (int r = 0; r < 4; r++) {
            const int lrow = rt * 16 + quad * 4 + r;
            const float ov = lrelu(acc2[rt][r] + bb) + xsv[rt][r];
            out[(size_t)(row0 + lrow) * FF + gcol] = ov;
            sA[lrow * XS_STRIDE + gcol] = f2bf(ov);
        }
    }
    __syncthreads();   // sA = bf16 out tile, visible to all waves

    // ---- Phase B: next layer's w1/w2/xt/diag from sA ----
    {
        const int g = tid >> 2;
        const int h = tid & 3;
        uint p[8];
#pragma unroll
        for (int jj = 0; jj < 8; jj++) {
            const uint lo = sA[(h * 16 + jj * 2) * XS_STRIDE + g];
            const uint hi = sA[(h * 16 + jj * 2 + 1) * XS_STRIDE + g];
            p[jj] = lo | (hi << 16);
        }
        uint4* dst = (uint4*)&xt[(size_t)b * (FF * NN) + (size_t)g * NN + jloc0 + h * 16];
        dst[0] = make_uint4(p[0], p[1], p[2], p[3]);
        dst[1] = make_uint4(p[4], p[5], p[6], p[7]);
    }

    f32x4 acc1n[4], acc2n[4];
#pragma unroll
    for (int rt = 0; rt < 4; rt++) { acc1n[rt] = (f32x4)0.f; acc2n[rt] = (f32x4)0.f; }

#pragma unroll
    for (int kk = 0; kk < 4; kk++) {
        short8 bf3 = *(const short8*)&w3t[n * 128 + kk * 32 + quad * 8];
        short8 bf4 = *(const short8*)&w4t[n * 128 + kk * 32 + quad * 8];
#pragma unroll
        for (int rt = 0; rt < 4; rt++) {
            short8 a = *(const short8*)&sA[(rt * 16 + c) * XS_STRIDE + kk * 32 + quad * 8];
            acc1n[rt] = __builtin_amdgcn_mfma_f32_16x16x32_bf16(a, bf3, acc1n[rt], 0, 0, 0);
            acc2n[rt] = __builtin_amdgcn_mfma_f32_16x16x32_bf16(a, bf4, acc2n[rt], 0, 0, 0);
        }
    }

    const float bb3 = b3[gcol], bb4 = b4[gcol];
    float dpar[4][4];
#pragma unroll
    for (int rt = 0; rt < 4; rt++) {
        ushort w2p[4];
#pragma unroll
        for (int r = 0; r < 4; r++) {
            const float v1 = lrelu(acc1n[rt][r] + bb3);
            const float v2 = lrelu(acc2n[rt][r] + bb4);
            const int grow = row0 + rt * 16 + quad * 4 + r;
            w1b[(size_t)grow * FF + gcol] = f2bf(v1);
            w2p[r] = f2bf(v2);
            dpar[rt][r] = v1 * v2;
        }
        const uint lo = (uint)w2p[0] | ((uint)w2p[1] << 16);
        const uint hi = (uint)w2p[2] | ((uint)w2p[3] << 16);
        uint2* dst = (uint2*)&w2t[(size_t)b * (FF * NN) + (size_t)gcol * NN +
                                  jloc0 + rt * 16 + quad * 4];
        *dst = make_uint2(lo, hi);
    }

#pragma unroll
    for (int rt = 0; rt < 4; rt++) {
#pragma unroll
        for (int r = 0; r < 4; r++) {
            float dp = dpar[rt][r];
            dp += __shfl_xor(dp, 1, 64);
            dp += __shfl_xor(dp, 2, 64);
            dp += __shfl_xor(dp, 4, 64);
            dp += __shfl_xor(dp, 8, 64);
            if (c == 0) atomicAdd(&diag_s[rt * 16 + quad * 4 + r], dp);
        }
    }
    __syncthreads();
    if (tid < 64) diag[row0 + tid] = diag_s[tid];
}

// ---------------------------------------------------------------------------
extern "C" void kernel_launch(void* const* d_in, const int* in_sizes, int n_in,
                              void* d_out, int out_size, void* d_ws, size_t ws_size,
                              hipStream_t stream)
{
    const float* x  = (const float*)d_in[0];
    const float* W3 = (const float*)d_in[1];
    const float* b3 = (const float*)d_in[2];
    const float* W4 = (const float*)d_in[3];
    const float* b4 = (const float*)d_in[4];
    const float* W5 = (const float*)d_in[5];
    const float* b5 = (const float*)d_in[6];
    float* out = (float*)d_out;

    char* ws = (char*)d_ws;
    ushort* w1b   = (ushort*)(ws);                       // 4 MB bf16 [16384][128]
    ushort* w2t   = (ushort*)(ws + ((size_t)4  << 20));  // 4 MB bf16 [8][128][2048]
    ushort* xt    = (ushort*)(ws + ((size_t)8  << 20));  // 4 MB bf16 [8][128][2048]
    float*  diag  = (float*) (ws + ((size_t)12 << 20));  // 64 KB fp32 [16384]
    ushort* St    = (ushort*)(ws + ((size_t)13 << 20));  // 256 KB bf16 [8][128][128]
    ushort* Wt    = (ushort*)(ws + ((size_t)14 << 20));  // 192 KB bf16 [6][128][128]

    const ushort* w3t0 = Wt;
    const ushort* w4t0 = Wt + 16384;
    const ushort* w5t0 = Wt + 2 * 16384;
    const ushort* w3t1 = Wt + 3 * 16384;
    const ushort* w4t1 = Wt + 4 * 16384;
    const ushort* w5t1 = Wt + 5 * 16384;

    const int rowBlocks = NROW / 64;   // 256

    k_prep<<<384, 256, 0, stream>>>(W3, W4, W5, Wt);

    // Layer 0
    k_w12<<<rowBlocks, 512, 0, stream>>>(x, w3t0, w4t0, b3, b4, w1b, w2t, xt, diag);
    k_S2<<<256, 256, 0, stream>>>(xt, w2t, St);
    // Layer 0 output + Layer 1 w12, fused
    k_out_w12<<<rowBlocks, 512, 0, stream>>>(x, w1b, St, diag, w5t0, b5, out,
                                             w3t1, w4t1, b3 + FF, b4 + FF,
                                             w1b, w2t, xt, diag);
    // Layer 1
    k_S2<<<256, 256, 0, stream>>>(xt, w2t, St);
    k_out<<<rowBlocks, 512, 0, stream>>>(out, w1b, St, diag, w5t1, b5 + FF, out);
}